// Round 1
// baseline (371.770 us; speedup 1.0000x reference)
//
#include <hip/hip_runtime.h>

typedef unsigned short u16;
typedef unsigned int u32;
typedef __attribute__((ext_vector_type(8))) __bf16 bh8;
typedef __attribute__((ext_vector_type(4))) float fx4;

#define AS1 __attribute__((address_space(1)))
#define AS3 __attribute__((address_space(3)))

__device__ __forceinline__ void gll16(const void* g, void* l) {
  void* gg = const_cast<void*>(g);
  __builtin_amdgcn_global_load_lds((AS1 void*)gg, (AS3 void*)l, 16, 0, 0);
}

__device__ __forceinline__ u16 f2b(float f) {
  union { float f; u32 u; } v; v.f = f;
  u32 r = v.u + 0x7FFFu + ((v.u >> 16) & 1u);
  return (u16)(r >> 16);
}

__device__ __forceinline__ fx4 fzero() { fx4 z = {0.f, 0.f, 0.f, 0.f}; return z; }

#define MFMA16(a, b, c) __builtin_amdgcn_mfma_f32_16x16x32_bf16(a, b, c, 0, 0, 0)

// ---------------- cast f32 -> bf16, vectorized ----------------
__global__ void k_cast(const float* __restrict__ in, u16* __restrict__ out, int n4) {
  int i = blockIdx.x * blockDim.x + threadIdx.x;
  if (i >= n4) return;
  float4 v = reinterpret_cast<const float4*>(in)[i];
  ushort4 o;
  o.x = f2b(v.x); o.y = f2b(v.y); o.z = f2b(v.z); o.w = f2b(v.w);
  reinterpret_cast<ushort4*>(out)[i] = o;
}

// ---------------- transpose + cast: W[R][C] f32 -> Wt[C][R] bf16 ----------------
__global__ void k_transpose_cast(const float* __restrict__ in, u16* __restrict__ out,
                                 int R, int C) {
  __shared__ float t[32][33];
  int tx = threadIdx.x, ty = threadIdx.y;
  int r0 = blockIdx.y * 32, c0 = blockIdx.x * 32;
#pragma unroll
  for (int j = 0; j < 4; j++)
    t[ty + 8 * j][tx] = in[(size_t)(r0 + ty + 8 * j) * C + c0 + tx];
  __syncthreads();
#pragma unroll
  for (int j = 0; j < 4; j++)
    out[(size_t)(c0 + ty + 8 * j) * R + r0 + tx] = f2b(t[tx][ty + 8 * j]);
}

// ---------------- transpose V (bf16): [(b*2048+s)*512 + kv*128 + d] -> [(z*128+d)*2048 + s]
__global__ void k_transpose_v(const u16* __restrict__ in, u16* __restrict__ out) {
  __shared__ u16 t[32][33];
  int tx = threadIdx.x, ty = threadIdx.y;
  int s0 = blockIdx.x * 32, d0 = blockIdx.y * 32;
  int z = blockIdx.z, b = z >> 2, kv = z & 3;
#pragma unroll
  for (int j = 0; j < 4; j++)
    t[ty + 8 * j][tx] = in[(size_t)(b * 2048 + s0 + ty + 8 * j) * 512 + kv * 128 + d0 + tx];
  __syncthreads();
#pragma unroll
  for (int j = 0; j < 4; j++)
    out[(size_t)(z * 128 + d0 + ty + 8 * j) * 2048 + s0 + tx] = t[tx][ty + 8 * j];
}

// ---------------- GEMM core: C[128x128 tile] = A[M][2048] * Bt[N][2048]^T ----------------
// 256 threads = 4 waves in 2x2; per-wave 64x64 = 4x4 fragments of 16x16x32 MFMA.
__device__ __forceinline__ void gemm_core(const u16* __restrict__ A, const u16* __restrict__ Bt,
                                          int bm, int bn, u16* As, u16* Bs, fx4 acc[4][4]) {
  const int tid = threadIdx.x;
  const int lane = tid & 63, w = tid >> 6;
  const int wr = w >> 1, wc = w & 1;
  const int i = lane & 15, g = lane >> 4;
  const int c0 = tid, c1 = tid + 256;
  const u16* ga0 = A + (size_t)(bm + (c0 >> 2)) * 2048 + (c0 & 3) * 8;
  const u16* ga1 = A + (size_t)(bm + (c1 >> 2)) * 2048 + (c1 & 3) * 8;
  const u16* gb0 = Bt + (size_t)(bn + (c0 >> 2)) * 2048 + (c0 & 3) * 8;
  const u16* gb1 = Bt + (size_t)(bn + (c1 >> 2)) * 2048 + (c1 & 3) * 8;
  u16* la0 = As + c0 * 8; u16* la1 = As + c1 * 8;
  u16* lb0 = Bs + c0 * 8; u16* lb1 = Bs + c1 * 8;
  const u16* ra = As + (wr * 64 + i) * 32 + g * 8;
  const u16* rb = Bs + (wc * 64 + i) * 32 + g * 8;
  for (int kt = 0; kt < 2048; kt += 32) {
    __syncthreads();
    gll16(ga0 + kt, la0);
    gll16(ga1 + kt, la1);
    gll16(gb0 + kt, lb0);
    gll16(gb1 + kt, lb1);
    __syncthreads();
    bh8 af[4], bfr[4];
#pragma unroll
    for (int m = 0; m < 4; m++) af[m] = *reinterpret_cast<const bh8*>(ra + m * 16 * 32);
#pragma unroll
    for (int n = 0; n < 4; n++) bfr[n] = *reinterpret_cast<const bh8*>(rb + n * 16 * 32);
#pragma unroll
    for (int m = 0; m < 4; m++)
#pragma unroll
      for (int n = 0; n < 4; n++)
        acc[m][n] = MFMA16(af[m], bfr[n], acc[m][n]);
  }
}

// ---------------- fused QKV projection GEMM ----------------
__global__ __launch_bounds__(256, 2) void k_proj(const u16* __restrict__ xb,
                                                 const u16* __restrict__ Wqt,
                                                 const u16* __restrict__ Wkt,
                                                 const u16* __restrict__ Wvt,
                                                 u16* __restrict__ Qb, u16* __restrict__ Kb,
                                                 u16* __restrict__ Vb) {
  __shared__ __align__(16) u16 As[128 * 32];
  __shared__ __align__(16) u16 Bs[128 * 32];
  int by = blockIdx.y;
  const u16* Bt; u16* Cp; int bn, ldc; float alpha;
  if (by < 16)      { Bt = Wqt; Cp = Qb; bn = by * 128;        ldc = 2048; alpha = 0.08838834764831845f; }
  else if (by < 20) { Bt = Wkt; Cp = Kb; bn = (by - 16) * 128; ldc = 512;  alpha = 1.0f; }
  else              { Bt = Wvt; Cp = Vb; bn = (by - 20) * 128; ldc = 512;  alpha = 1.0f; }
  int bm = blockIdx.x * 128;
  fx4 acc[4][4];
#pragma unroll
  for (int m = 0; m < 4; m++)
#pragma unroll
    for (int n = 0; n < 4; n++) acc[m][n] = fzero();
  gemm_core(xb, Bt, bm, bn, As, Bs, acc);
  const int lane = threadIdx.x & 63, w = threadIdx.x >> 6;
  const int wr = w >> 1, wc = w & 1, i = lane & 15, g = lane >> 4;
#pragma unroll
  for (int m = 0; m < 4; m++)
#pragma unroll
    for (int n = 0; n < 4; n++)
#pragma unroll
      for (int r = 0; r < 4; r++) {
        int row = bm + wr * 64 + m * 16 + 4 * g + r;
        int col = bn + wc * 64 + n * 16 + i;
        Cp[(size_t)row * ldc + col] = f2b(acc[m][n][r] * alpha);
      }
}

// ---------------- output GEMM (f32 out) ----------------
__global__ __launch_bounds__(256, 2) void k_gemm_out(const u16* __restrict__ Ob,
                                                     const u16* __restrict__ Wot,
                                                     float* __restrict__ C) {
  __shared__ __align__(16) u16 As[128 * 32];
  __shared__ __align__(16) u16 Bs[128 * 32];
  int bm = blockIdx.x * 128, bn = blockIdx.y * 128;
  fx4 acc[4][4];
#pragma unroll
  for (int m = 0; m < 4; m++)
#pragma unroll
    for (int n = 0; n < 4; n++) acc[m][n] = fzero();
  gemm_core(Ob, Wot, bm, bn, As, Bs, acc);
  const int lane = threadIdx.x & 63, w = threadIdx.x >> 6;
  const int wr = w >> 1, wc = w & 1, i = lane & 15, g = lane >> 4;
#pragma unroll
  for (int m = 0; m < 4; m++)
#pragma unroll
    for (int n = 0; n < 4; n++)
#pragma unroll
      for (int r = 0; r < 4; r++) {
        int row = bm + wr * 64 + m * 16 + 4 * g + r;
        int col = bn + wc * 64 + n * 16 + i;
        C[(size_t)row * 2048 + col] = acc[m][n][r];
      }
}

// ---------------- flash attention (causal, GQA) ----------------
// grid: (S/64, 16 heads, B). 4 waves; wave w owns q rows [qb+16w, qb+16w+16).
// K tile [64][128] and V^T tile [128][64] staged via global_load_lds with
// XOR-swizzled source so swizzled ds_read_b128 is ~conflict-free.
__global__ __launch_bounds__(256, 2) void k_attn(const u16* __restrict__ Qb,
                                                 const u16* __restrict__ Kb,
                                                 const u16* __restrict__ Vt,
                                                 u16* __restrict__ Ob) {
  __shared__ __align__(16) u16 Ks[64 * 128];
  __shared__ __align__(16) u16 Vs[128 * 64];
  __shared__ __align__(16) u16 Pl[4][16 * 72];
  const int tid = threadIdx.x, lane = tid & 63, w = tid >> 6;
  const int i = lane & 15, g = lane >> 4;
  const int qb = blockIdx.x * 64;
  const int head = blockIdx.y, b = blockIdx.z, kv = head >> 2;
  const int qmin = qb + w * 16;

  // Q fragments (pre-scaled by 1/sqrt(128) in the projection)
  const u16* qptr = Qb + (size_t)(b * 2048 + qmin + i) * 2048 + head * 128 + g * 8;
  bh8 qf[4];
#pragma unroll
  for (int kb = 0; kb < 4; kb++) qf[kb] = *reinterpret_cast<const bh8*>(qptr + kb * 32);

  fx4 o[8];
#pragma unroll
  for (int dt = 0; dt < 8; dt++) o[dt] = fzero();
  float m[4] = {-1e30f, -1e30f, -1e30f, -1e30f};
  float l[4] = {0.f, 0.f, 0.f, 0.f};

  for (int s0 = 0; s0 < qb + 64; s0 += 64) {
    __syncthreads();
#pragma unroll
    for (int cc = 0; cc < 4; cc++) {
      int c = tid + cc * 256;
      // K: 64 rows x 16 granules; source granule pre-swizzled by row&7
      gll16(Kb + (size_t)(b * 2048 + s0 + (c >> 4)) * 512 + kv * 128 +
                (((c & 15) ^ ((c >> 4) & 7)) * 8),
            Ks + c * 8);
      // V^T: 128 rows x 8 granules
      gll16(Vt + (size_t)((b * 4 + kv) * 128 + (c >> 3)) * 2048 + s0 +
                (((c & 7) ^ ((c >> 3) & 7)) * 8),
            Vs + c * 8);
    }
    __syncthreads();

    // scores: 4 s-subtiles of 16
    fx4 sc[4];
#pragma unroll
    for (int st = 0; st < 4; st++) {
      sc[st] = fzero();
#pragma unroll
      for (int kb = 0; kb < 4; kb++) {
        bh8 kf = *reinterpret_cast<const bh8*>(Ks + (st * 16 + i) * 128 +
                                               (((kb * 4 + g) ^ (i & 7)) * 8));
        sc[st] = MFMA16(qf[kb], kf, sc[st]);
      }
    }

    // causal mask (only near diagonal)
    if (s0 + 63 > qmin) {
#pragma unroll
      for (int st = 0; st < 4; st++)
#pragma unroll
        for (int r = 0; r < 4; r++) {
          int s = s0 + st * 16 + i;
          int q = qmin + 4 * g + r;
          if (s > q) sc[st][r] = -1e30f;
        }
    }

    // online softmax (row q = 4g+r lives on 16 lanes sharing g)
    float corr[4];
#pragma unroll
    for (int r = 0; r < 4; r++) {
      float v = fmaxf(fmaxf(sc[0][r], sc[1][r]), fmaxf(sc[2][r], sc[3][r]));
      v = fmaxf(v, __shfl_xor(v, 1));
      v = fmaxf(v, __shfl_xor(v, 2));
      v = fmaxf(v, __shfl_xor(v, 4));
      v = fmaxf(v, __shfl_xor(v, 8));
      float mn = fmaxf(m[r], v);
      corr[r] = __expf(m[r] - mn);
      m[r] = mn;
    }
    float p[4][4];
#pragma unroll
    for (int r = 0; r < 4; r++) {
      float s = 0.f;
#pragma unroll
      for (int st = 0; st < 4; st++) { p[st][r] = __expf(sc[st][r] - m[r]); s += p[st][r]; }
      s += __shfl_xor(s, 1); s += __shfl_xor(s, 2);
      s += __shfl_xor(s, 4); s += __shfl_xor(s, 8);
      l[r] = l[r] * corr[r] + s;
    }
#pragma unroll
    for (int dt = 0; dt < 8; dt++)
#pragma unroll
      for (int r = 0; r < 4; r++) o[dt][r] *= corr[r];

    // P -> LDS (per-wave buffer, padded rows: 72 elems = 144B, conflict-benign)
#pragma unroll
    for (int st = 0; st < 4; st++)
#pragma unroll
      for (int r = 0; r < 4; r++)
        Pl[w][(4 * g + r) * 72 + st * 16 + i] = f2b(p[st][r]);

    bh8 pf0 = *reinterpret_cast<const bh8*>(&Pl[w][i * 72 + g * 8]);
    bh8 pf1 = *reinterpret_cast<const bh8*>(&Pl[w][i * 72 + 32 + g * 8]);
#pragma unroll
    for (int dt = 0; dt < 8; dt++) {
      bh8 v0 = *reinterpret_cast<const bh8*>(Vs + (dt * 16 + i) * 64 + (((g) ^ (i & 7)) * 8));
      bh8 v1 = *reinterpret_cast<const bh8*>(Vs + (dt * 16 + i) * 64 + (((4 + g) ^ (i & 7)) * 8));
      o[dt] = MFMA16(pf0, v0, o[dt]);
      o[dt] = MFMA16(pf1, v1, o[dt]);
    }
  }

  // epilogue: normalize and store
#pragma unroll
  for (int r = 0; r < 4; r++) {
    float inv = 1.0f / l[r];
#pragma unroll
    for (int dt = 0; dt < 8; dt++)
      Ob[(size_t)(b * 2048 + qmin + 4 * g + r) * 2048 + head * 128 + dt * 16 + i] =
          f2b(o[dt][r] * inv);
  }
}

extern "C" void kernel_launch(void* const* d_in, const int* in_sizes, int n_in,
                              void* d_out, int out_size, void* d_ws, size_t ws_size,
                              hipStream_t stream) {
  (void)in_sizes; (void)n_in; (void)out_size; (void)ws_size;
  const float* x  = (const float*)d_in[0];
  const float* Wq = (const float*)d_in[1];
  const float* Wk = (const float*)d_in[2];
  const float* Wv = (const float*)d_in[3];
  const float* Wo = (const float*)d_in[4];

  char* ws = (char*)d_ws;
  size_t off = 0;
  auto alloc = [&](size_t bytes) {
    void* p = ws + off;
    off += (bytes + 255) & ~(size_t)255;
    return p;
  };
  u16* xb  = (u16*)alloc(8388608ull * 2);  // x bf16; reused as Ob after proj
  u16* Wqt = (u16*)alloc(4194304ull * 2);
  u16* Wkt = (u16*)alloc(1048576ull * 2);
  u16* Wvt = (u16*)alloc(1048576ull * 2);
  u16* Wot = (u16*)alloc(4194304ull * 2);
  u16* Qb  = (u16*)alloc(8388608ull * 2);
  u16* Kb  = (u16*)alloc(2097152ull * 2);
  u16* Vb  = (u16*)alloc(2097152ull * 2);
  u16* Vt  = (u16*)alloc(2097152ull * 2);
  u16* Ob  = xb;  // x is dead after k_proj

  k_cast<<<8192, 256, 0, stream>>>(x, xb, 2097152);
  k_transpose_cast<<<dim3(64, 64), dim3(32, 8), 0, stream>>>(Wq, Wqt, 2048, 2048);
  k_transpose_cast<<<dim3(16, 64), dim3(32, 8), 0, stream>>>(Wk, Wkt, 2048, 512);
  k_transpose_cast<<<dim3(16, 64), dim3(32, 8), 0, stream>>>(Wv, Wvt, 2048, 512);
  k_transpose_cast<<<dim3(64, 64), dim3(32, 8), 0, stream>>>(Wo, Wot, 2048, 2048);
  k_proj<<<dim3(32, 24), 256, 0, stream>>>(xb, Wqt, Wkt, Wvt, Qb, Kb, Vb);
  k_transpose_v<<<dim3(64, 4, 8), dim3(32, 8), 0, stream>>>(Vb, Vt);
  k_attn<<<dim3(32, 16, 2), 256, 0, stream>>>(Qb, Kb, Vt, Ob);
  k_gemm_out<<<dim3(32, 16), 256, 0, stream>>>(Ob, Wot, (float*)d_out);
}